// Round 2
// baseline (18846.764 us; speedup 1.0000x reference)
//
#include <hip/hip_runtime.h>
#include <math.h>

#define HH 20
#define PP 64

__device__ __forceinline__ double elu_d(double v) { return v > 0.0 ? v : expm1(v); }
__device__ __forceinline__ float  elu_f(float v)  { return v > 0.0f ? v : expm1f(v); }

// order-preserving double<->u64 encoding for atomicMax
__device__ __forceinline__ unsigned long long fenc64(double f) {
    unsigned long long u = __builtin_bit_cast(unsigned long long, f);
    return (u & 0x8000000000000000ull) ? ~u : (u | 0x8000000000000000ull);
}
__device__ __forceinline__ double fdec64(unsigned long long u) {
    unsigned long long b = (u & 0x8000000000000000ull) ? (u & 0x7fffffffffffffffull) : ~u;
    return __builtin_bit_cast(double, b);
}

__global__ __launch_bounds__(64) void dgcnn_fused(
    const float* __restrict__ x,
    const float* __restrict__ Wi0, const float* __restrict__ bi0,
    const float* __restrict__ Wi1, const float* __restrict__ bi1,
    const float* __restrict__ Wi2, const float* __restrict__ bi2,
    const float* __restrict__ We0a, const float* __restrict__ be0a,
    const float* __restrict__ We0b, const float* __restrict__ be0b,
    const float* __restrict__ We1a, const float* __restrict__ be1a,
    const float* __restrict__ We1b, const float* __restrict__ be1b,
    const float* __restrict__ Wo0, const float* __restrict__ bo0,
    const float* __restrict__ Wo1, const float* __restrict__ bo1,
    const float* __restrict__ Wo2, const float* __restrict__ bo2,
    float* __restrict__ out)
{
    const int b = blockIdx.x;
    const int p = threadIdx.x;

    __shared__ __align__(16) double hbuf[PP][HH];   // 160B rows, 16B aligned
    __shared__ double sqv[PP];
    __shared__ float  vflag[PP];
    __shared__ int    cflag[PP];

    // ---------------- input MLP: 3 -> 20 -> 20 -> 20 (f64) ----------------
    double h[HH];
    {
        const size_t xb = (size_t)b * (PP * 3) + (size_t)p * 3;
        const double x0 = (double)x[xb + 0];
        const double x1 = (double)x[xb + 1];
        const double x2 = (double)x[xb + 2];
        double a[HH], t[HH];
        #pragma unroll
        for (int j = 0; j < HH; ++j)
            a[j] = fma(x2, (double)Wi0[2*HH + j],
                   fma(x1, (double)Wi0[HH + j],
                   fma(x0, (double)Wi0[j], (double)bi0[j])));
        #pragma unroll
        for (int j = 0; j < HH; ++j) t[j] = elu_d(a[j]);

        #pragma unroll
        for (int j = 0; j < HH; ++j) a[j] = (double)bi1[j];
        #pragma unroll
        for (int d = 0; d < HH; ++d) {
            #pragma unroll
            for (int j = 0; j < HH; ++j)
                a[j] = fma(t[d], (double)Wi1[d*HH + j], a[j]);
        }
        #pragma unroll
        for (int j = 0; j < HH; ++j) t[j] = elu_d(a[j]);

        #pragma unroll
        for (int j = 0; j < HH; ++j) a[j] = (double)bi2[j];
        #pragma unroll
        for (int d = 0; d < HH; ++d) {
            #pragma unroll
            for (int j = 0; j < HH; ++j)
                a[j] = fma(t[d], (double)Wi2[d*HH + j], a[j]);
        }
        #pragma unroll
        for (int j = 0; j < HH; ++j) h[j] = elu_d(a[j]);
    }
    double vp = 1.0;

    // ---------------- two EdgeConv + pool blocks (f64) ----------------
    #pragma unroll 1
    for (int blk = 0; blk < 2; ++blk) {
        const float* Wa = blk ? We1a : We0a;
        const float* ba = blk ? be1a : be0a;
        const float* Wb = blk ? We1b : We0b;
        const float* bb = blk ? be1b : be0b;

        double sqp = 0.0;
        #pragma unroll
        for (int d = 0; d < HH; ++d) sqp = fma(h[d], h[d], sqp);
        #pragma unroll
        for (int j2 = 0; j2 < HH; j2 += 2)
            *(double2*)&hbuf[p][j2] = make_double2(h[j2], h[j2+1]);
        sqv[p]   = sqp;
        vflag[p] = (float)vp;
        __syncthreads();

        // ---- knn top-4, lexicographic (score, -index), all in f64 ----
        double s0=-INFINITY, s1=-INFINITY, s2=-INFINITY, s3=-INFINITY;
        int    i0=PP, i1=PP, i2=PP, i3=PP;
        #pragma unroll 2
        for (int q = 0; q < PP; ++q) {
            double dot = 0.0;
            #pragma unroll
            for (int j2 = 0; j2 < HH; j2 += 2) {
                double2 r = *(const double2*)&hbuf[q][j2];
                dot = fma(r.y, h[j2+1], fma(r.x, h[j2], dot));
            }
            double s = 2.0*dot - sqp - sqv[q];
            if (q == p || vflag[q] == 0.0f) s = -INFINITY;
            bool b0 = (s > s0) || (s == s0 && q < i0);
            bool b1 = (s > s1) || (s == s1 && q < i1);
            bool b2 = (s > s2) || (s == s2 && q < i2);
            bool b3 = (s > s3) || (s == s3 && q < i3);
            s3 = b2 ? s2 : (b3 ? s : s3);  i3 = b2 ? i2 : (b3 ? q : i3);
            s2 = b1 ? s1 : (b2 ? s : s2);  i2 = b1 ? i1 : (b2 ? q : i2);
            s1 = b0 ? s0 : (b1 ? s : s1);  i1 = b0 ? i0 : (b1 ? q : i1);
            s0 = b0 ? s  : s0;             i0 = b0 ? q  : i0;
        }

        // ---- EdgeConv ----
        double base[HH];
        #pragma unroll
        for (int j = 0; j < HH; ++j) base[j] = (double)ba[j];
        #pragma unroll
        for (int d = 0; d < HH; ++d) {
            #pragma unroll
            for (int j = 0; j < HH; ++j)
                base[j] = fma(h[d], (double)Wa[d*HH + j], base[j]);
        }
        double hsum[HH];
        #pragma unroll
        for (int j = 0; j < HH; ++j) hsum[j] = 0.0;

        #pragma unroll 1
        for (int k = 0; k < 4; ++k) {
            const int jn = (k == 0) ? i0 : (k == 1) ? i1 : (k == 2) ? i2 : i3;
            const double vn = (double)vflag[jn];
            double xd[HH];
            #pragma unroll
            for (int j2 = 0; j2 < HH; j2 += 2) {
                double2 r = *(const double2*)&hbuf[jn][j2];
                xd[j2]   = r.x - h[j2];
                xd[j2+1] = r.y - h[j2+1];
            }
            double m1[HH];
            #pragma unroll
            for (int j = 0; j < HH; ++j) m1[j] = base[j];
            #pragma unroll
            for (int d = 0; d < HH; ++d) {
                #pragma unroll
                for (int j = 0; j < HH; ++j)
                    m1[j] = fma(xd[d], (double)Wa[(HH + d)*HH + j], m1[j]);
            }
            #pragma unroll
            for (int j = 0; j < HH; ++j) m1[j] = elu_d(m1[j]);

            double m2[HH];
            #pragma unroll
            for (int j = 0; j < HH; ++j) m2[j] = (double)bb[j];
            #pragma unroll
            for (int d = 0; d < HH; ++d) {
                #pragma unroll
                for (int j = 0; j < HH; ++j)
                    m2[j] = fma(m1[d], (double)Wb[d*HH + j], m2[j]);
            }
            #pragma unroll
            for (int j = 0; j < HH; ++j)
                hsum[j] = fma(elu_d(m2[j]), vn, hsum[j]);
        }
        #pragma unroll
        for (int j = 0; j < HH; ++j) hsum[j] *= vp;
        __syncthreads();   // all lanes done reading hbuf

        // ---- pool: cluster = min(p, nn0), scatter-max (u64-encoded f64) ----
        unsigned long long* pbuf = (unsigned long long*)&hbuf[0][0];
        #pragma unroll
        for (int j = 0; j < HH; ++j) pbuf[p*HH + j] = 0ull;  // < fenc64(anything)
        cflag[p] = 0;
        __syncthreads();
        {
            const int c = min(p, i0);
            if (vp != 0.0) {
                cflag[c] = 1;                       // benign same-value race
                #pragma unroll
                for (int j = 0; j < HH; ++j)
                    atomicMax(&pbuf[c*HH + j], fenc64(hsum[j]));
            }
        }
        __syncthreads();
        {
            const int nv = cflag[p];
            vp = nv ? 1.0 : 0.0;
            #pragma unroll
            for (int j = 0; j < HH; ++j)
                h[j] = nv ? fdec64(pbuf[p*HH + j]) : 0.0;
        }
        __syncthreads();
    }

    // ---------------- continuous tail in f32 ----------------
    float hf[HH];
    #pragma unroll
    for (int j = 0; j < HH; ++j) hf[j] = (vp != 0.0) ? (float)h[j] : -INFINITY;
    #pragma unroll
    for (int s = 1; s < 64; s <<= 1) {
        #pragma unroll
        for (int j = 0; j < HH; ++j)
            hf[j] = fmaxf(hf[j], __shfl_xor(hf[j], s));
    }

    float o1[HH], o2[HH], lg[10];
    #pragma unroll
    for (int j = 0; j < HH; ++j) o1[j] = bo0[j];
    #pragma unroll
    for (int d = 0; d < HH; ++d) {
        #pragma unroll
        for (int j = 0; j < HH; ++j) o1[j] = fmaf(hf[d], Wo0[d*HH + j], o1[j]);
    }
    #pragma unroll
    for (int j = 0; j < HH; ++j) o1[j] = elu_f(o1[j]);
    #pragma unroll
    for (int j = 0; j < HH; ++j) o2[j] = bo1[j];
    #pragma unroll
    for (int d = 0; d < HH; ++d) {
        #pragma unroll
        for (int j = 0; j < HH; ++j) o2[j] = fmaf(o1[d], Wo1[d*HH + j], o2[j]);
    }
    #pragma unroll
    for (int j = 0; j < HH; ++j) o2[j] = elu_f(o2[j]);
    #pragma unroll
    for (int j = 0; j < 10; ++j) lg[j] = bo2[j];
    #pragma unroll
    for (int d = 0; d < HH; ++d) {
        #pragma unroll
        for (int j = 0; j < 10; ++j) lg[j] = fmaf(o2[d], Wo2[d*10 + j], lg[j]);
    }
    float m = lg[0];
    #pragma unroll
    for (int j = 1; j < 10; ++j) m = fmaxf(m, lg[j]);
    float ssum = 0.0f;
    #pragma unroll
    for (int j = 0; j < 10; ++j) ssum += expf(lg[j] - m);
    const float lse = m + logf(ssum);
    if (p < 10) {
        float v = 0.0f;
        #pragma unroll
        for (int j = 0; j < 10; ++j) v = (p == j) ? lg[j] : v;
        out[(size_t)b * 10 + p] = v - lse;
    }
}

extern "C" void kernel_launch(void* const* d_in, const int* in_sizes, int n_in,
                              void* d_out, int out_size, void* d_ws, size_t ws_size,
                              hipStream_t stream) {
    const float* x    = (const float*)d_in[0];
    const float* Wi0  = (const float*)d_in[1];
    const float* bi0  = (const float*)d_in[2];
    const float* Wi1  = (const float*)d_in[3];
    const float* bi1  = (const float*)d_in[4];
    const float* Wi2  = (const float*)d_in[5];
    const float* bi2  = (const float*)d_in[6];
    const float* We0a = (const float*)d_in[7];
    const float* be0a = (const float*)d_in[8];
    const float* We0b = (const float*)d_in[9];
    const float* be0b = (const float*)d_in[10];
    const float* We1a = (const float*)d_in[11];
    const float* be1a = (const float*)d_in[12];
    const float* We1b = (const float*)d_in[13];
    const float* be1b = (const float*)d_in[14];
    const float* Wo0  = (const float*)d_in[15];
    const float* bo0  = (const float*)d_in[16];
    const float* Wo1  = (const float*)d_in[17];
    const float* bo1  = (const float*)d_in[18];
    const float* Wo2  = (const float*)d_in[19];
    const float* bo2  = (const float*)d_in[20];
    float* out = (float*)d_out;

    dgcnn_fused<<<dim3(8192), dim3(64), 0, stream>>>(
        x, Wi0, bi0, Wi1, bi1, Wi2, bi2,
        We0a, be0a, We0b, be0b, We1a, be1a, We1b, be1b,
        Wo0, bo0, Wo1, bo1, Wo2, bo2, out);
}

// Round 3
// 6553.333 us; speedup vs baseline: 2.8759x; 2.8759x over previous
//
#include <hip/hip_runtime.h>
#include <math.h>

#define HH 20
#define HP 21      // padded LDS row stride (doubles)
#define PP 64

// compact expm1 for v<=0: absolute error ~2e-16, result in (-1,0]
__device__ __forceinline__ double expm1_neg(double v) {
    if (v <= -40.0) return -1.0;
    const double LOG2E  = 1.4426950408889634074e+00;
    const double LN2_HI = 6.93147180369123816490e-01;
    const double LN2_LO = 1.90821492927058770002e-10;
    double nd = rint(v * LOG2E);
    double r  = fma(-nd, LN2_HI, v);
    r = fma(-nd, LN2_LO, r);
    double p = 2.08767569878680989792e-09;          // 1/12!
    p = fma(p, r, 2.50521083854417187751e-08);      // 1/11!
    p = fma(p, r, 2.75573192239858906526e-07);      // 1/10!
    p = fma(p, r, 2.75573192239858925110e-06);      // 1/9!
    p = fma(p, r, 2.48015873015873015873e-05);      // 1/8!
    p = fma(p, r, 1.98412698412698412698e-04);      // 1/7!
    p = fma(p, r, 1.38888888888888888889e-03);      // 1/6!
    p = fma(p, r, 8.33333333333333333333e-03);      // 1/5!
    p = fma(p, r, 4.16666666666666666667e-02);      // 1/4!
    p = fma(p, r, 1.66666666666666666667e-01);      // 1/3!
    p = fma(p, r, 5.0e-01);                         // 1/2!
    p = fma(p, r, 1.0);
    p = fma(p, r, 1.0);
    long long n = (long long)nd;
    double sc = __builtin_bit_cast(double, (unsigned long long)(1023ll + n) << 52);
    return fma(p, sc, -1.0);
}
__device__ __forceinline__ double elu_d(double v) { return v > 0.0 ? v : expm1_neg(v); }
__device__ __forceinline__ float  elu_f(float v)  { return v > 0.0f ? v : expm1f(v); }

// order-preserving double<->u64 encoding for atomicMax
__device__ __forceinline__ unsigned long long fenc64(double f) {
    unsigned long long u = __builtin_bit_cast(unsigned long long, f);
    return (u & 0x8000000000000000ull) ? ~u : (u | 0x8000000000000000ull);
}
__device__ __forceinline__ double fdec64(unsigned long long u) {
    unsigned long long b = (u & 0x8000000000000000ull) ? (u & 0x7fffffffffffffffull) : ~u;
    return __builtin_bit_cast(double, b);
}

__global__ __launch_bounds__(64, 2) void dgcnn_fused(
    const float* __restrict__ x,
    const float* __restrict__ Wi0, const float* __restrict__ bi0,
    const float* __restrict__ Wi1, const float* __restrict__ bi1,
    const float* __restrict__ Wi2, const float* __restrict__ bi2,
    const float* __restrict__ We0a, const float* __restrict__ be0a,
    const float* __restrict__ We0b, const float* __restrict__ be0b,
    const float* __restrict__ We1a, const float* __restrict__ be1a,
    const float* __restrict__ We1b, const float* __restrict__ be1b,
    const float* __restrict__ Wo0, const float* __restrict__ bo0,
    const float* __restrict__ Wo1, const float* __restrict__ bo1,
    const float* __restrict__ Wo2, const float* __restrict__ bo2,
    float* __restrict__ out)
{
    const int b = blockIdx.x;
    const int p = threadIdx.x;

    __shared__ __align__(16) double hbuf[PP][HP];   // 10752 B
    __shared__ double sqv[PP];
    __shared__ int    ivld[PP];
    __shared__ int    cflag[PP];

    // ---------------- input MLP: 3 -> 20 -> 20 -> 20 (f64) ----------------
    double h[HH];
    {
        const size_t xb = (size_t)b * (PP * 3) + (size_t)p * 3;
        const double x0 = (double)x[xb + 0];
        const double x1 = (double)x[xb + 1];
        const double x2 = (double)x[xb + 2];
        double t[HH];
        #pragma unroll
        for (int j = 0; j < HH; ++j)
            t[j] = elu_d(fma(x2, (double)Wi0[2*HH + j],
                         fma(x1, (double)Wi0[HH + j],
                         fma(x0, (double)Wi0[j], (double)bi0[j]))));
        #pragma unroll
        for (int j = 0; j < HH; ++j) h[j] = (double)bi1[j];
        #pragma unroll 2
        for (int d = 0; d < HH; ++d) {
            const double td = t[d];
            #pragma unroll
            for (int j = 0; j < HH; ++j)
                h[j] = fma(td, (double)Wi1[d*HH + j], h[j]);
        }
        #pragma unroll
        for (int j = 0; j < HH; ++j) t[j] = elu_d(h[j]);
        #pragma unroll
        for (int j = 0; j < HH; ++j) h[j] = (double)bi2[j];
        #pragma unroll 2
        for (int d = 0; d < HH; ++d) {
            const double td = t[d];
            #pragma unroll
            for (int j = 0; j < HH; ++j)
                h[j] = fma(td, (double)Wi2[d*HH + j], h[j]);
        }
        #pragma unroll
        for (int j = 0; j < HH; ++j) h[j] = elu_d(h[j]);
    }
    int myvalid = 1;

    // ---------------- two EdgeConv + pool blocks (f64) ----------------
    #pragma unroll 1
    for (int blk = 0; blk < 2; ++blk) {
        const float* Wa = blk ? We1a : We0a;
        const float* ba = blk ? be1a : be0a;
        const float* Wb = blk ? We1b : We0b;
        const float* bb = blk ? be1b : be0b;

        double sqp = 0.0;
        #pragma unroll
        for (int d = 0; d < HH; ++d) sqp = fma(h[d], h[d], sqp);
        #pragma unroll
        for (int j = 0; j < HH; ++j) hbuf[p][j] = h[j];
        sqv[p]  = sqp;
        ivld[p] = myvalid;
        __syncthreads();

        // ---- knn top-4, lexicographic (score, -index), f64 ----
        double s0=-INFINITY, s1=-INFINITY, s2=-INFINITY, s3=-INFINITY;
        int    i0=PP, i1=PP, i2=PP, i3=PP;
        #pragma unroll 2
        for (int q = 0; q < PP; ++q) {
            double dot = 0.0;
            #pragma unroll
            for (int d = 0; d < HH; ++d)
                dot = fma(hbuf[q][d], h[d], dot);
            double s = 2.0*dot - sqp - sqv[q];
            if (q == p || ivld[q] == 0) s = -INFINITY;
            bool b0 = (s > s0) || (s == s0 && q < i0);
            bool b1 = (s > s1) || (s == s1 && q < i1);
            bool b2 = (s > s2) || (s == s2 && q < i2);
            bool b3 = (s > s3) || (s == s3 && q < i3);
            s3 = b2 ? s2 : (b3 ? s : s3);  i3 = b2 ? i2 : (b3 ? q : i3);
            s2 = b1 ? s1 : (b2 ? s : s2);  i2 = b1 ? i1 : (b2 ? q : i2);
            s1 = b0 ? s0 : (b1 ? s : s1);  i1 = b0 ? i0 : (b1 ? q : i1);
            s0 = b0 ? s  : s0;             i0 = b0 ? q  : i0;
        }

        // ---- EdgeConv: base folds the xi contribution of layer A ----
        double base[HH];
        #pragma unroll
        for (int j = 0; j < HH; ++j) base[j] = (double)ba[j];
        #pragma unroll 2
        for (int d = 0; d < HH; ++d) {
            const double hd = h[d];
            #pragma unroll
            for (int j = 0; j < HH; ++j) {
                const double wd = (double)Wa[d*HH + j] - (double)Wa[(HH + d)*HH + j];
                base[j] = fma(hd, wd, base[j]);
            }
        }
        double hsum[HH];
        #pragma unroll
        for (int j = 0; j < HH; ++j) hsum[j] = 0.0;

        #pragma unroll 1
        for (int kp = 0; kp < 2; ++kp) {   // neighbor pairs (i0,i1), (i2,i3)
            const int ja = kp ? i2 : i0;
            const int jb = kp ? i3 : i1;
            const double va = (double)ivld[ja];
            const double vb = (double)ivld[jb];

            double m1a[HH], m1b[HH];
            #pragma unroll
            for (int j = 0; j < HH; ++j) { m1a[j] = base[j]; m1b[j] = base[j]; }
            #pragma unroll 2
            for (int d = 0; d < HH; ++d) {
                const double qa = hbuf[ja][d];
                const double qb = hbuf[jb][d];
                #pragma unroll
                for (int j = 0; j < HH; ++j) {
                    const double w = (double)Wa[(HH + d)*HH + j];
                    m1a[j] = fma(qa, w, m1a[j]);
                    m1b[j] = fma(qb, w, m1b[j]);
                }
            }
            #pragma unroll
            for (int j = 0; j < HH; ++j) { m1a[j] = elu_d(m1a[j]); m1b[j] = elu_d(m1b[j]); }

            #pragma unroll
            for (int j = 0; j < HH; ++j) {
                double a0 = (double)bb[j], a1 = a0;
                #pragma unroll
                for (int d = 0; d < HH; ++d) {
                    const double w = (double)Wb[d*HH + j];
                    a0 = fma(m1a[d], w, a0);
                    a1 = fma(m1b[d], w, a1);
                }
                hsum[j] = fma(elu_d(a0), va, hsum[j]);
                hsum[j] = fma(elu_d(a1), vb, hsum[j]);
            }
        }
        {
            const double vpd = (double)myvalid;
            #pragma unroll
            for (int j = 0; j < HH; ++j) hsum[j] *= vpd;
        }
        __syncthreads();   // all lanes done reading hbuf

        // ---- pool: cluster = min(p, nn0), scatter-max (u64-encoded f64) ----
        unsigned long long* pbuf = (unsigned long long*)&hbuf[0][0];
        #pragma unroll
        for (int j = 0; j < HH; ++j) pbuf[p*HH + j] = 0ull;  // < fenc64(anything)
        cflag[p] = 0;
        __syncthreads();
        {
            const int c = min(p, i0);
            if (myvalid) {
                cflag[c] = 1;                       // benign same-value race
                #pragma unroll
                for (int j = 0; j < HH; ++j)
                    atomicMax(&pbuf[c*HH + j], fenc64(hsum[j]));
            }
        }
        __syncthreads();
        {
            const int nv = cflag[p];
            myvalid = nv;
            #pragma unroll
            for (int j = 0; j < HH; ++j)
                h[j] = nv ? fdec64(pbuf[p*HH + j]) : 0.0;
        }
        __syncthreads();
    }

    // ---------------- continuous tail in f32 ----------------
    float hf[HH];
    #pragma unroll
    for (int j = 0; j < HH; ++j) hf[j] = myvalid ? (float)h[j] : -INFINITY;
    #pragma unroll
    for (int s = 1; s < 64; s <<= 1) {
        #pragma unroll
        for (int j = 0; j < HH; ++j)
            hf[j] = fmaxf(hf[j], __shfl_xor(hf[j], s));
    }

    float o1[HH], o2[HH], lg[10];
    #pragma unroll
    for (int j = 0; j < HH; ++j) o1[j] = bo0[j];
    #pragma unroll 2
    for (int d = 0; d < HH; ++d) {
        #pragma unroll
        for (int j = 0; j < HH; ++j) o1[j] = fmaf(hf[d], Wo0[d*HH + j], o1[j]);
    }
    #pragma unroll
    for (int j = 0; j < HH; ++j) o1[j] = elu_f(o1[j]);
    #pragma unroll
    for (int j = 0; j < HH; ++j) o2[j] = bo1[j];
    #pragma unroll 2
    for (int d = 0; d < HH; ++d) {
        #pragma unroll
        for (int j = 0; j < HH; ++j) o2[j] = fmaf(o1[d], Wo1[d*HH + j], o2[j]);
    }
    #pragma unroll
    for (int j = 0; j < HH; ++j) o2[j] = elu_f(o2[j]);
    #pragma unroll
    for (int j = 0; j < 10; ++j) lg[j] = bo2[j];
    #pragma unroll 2
    for (int d = 0; d < HH; ++d) {
        #pragma unroll
        for (int j = 0; j < 10; ++j) lg[j] = fmaf(o2[d], Wo2[d*10 + j], lg[j]);
    }
    float m = lg[0];
    #pragma unroll
    for (int j = 1; j < 10; ++j) m = fmaxf(m, lg[j]);
    float ssum = 0.0f;
    #pragma unroll
    for (int j = 0; j < 10; ++j) ssum += expf(lg[j] - m);
    const float lse = m + logf(ssum);
    if (p < 10) {
        float v = 0.0f;
        #pragma unroll
        for (int j = 0; j < 10; ++j) v = (p == j) ? lg[j] : v;
        out[(size_t)b * 10 + p] = v - lse;
    }
}

extern "C" void kernel_launch(void* const* d_in, const int* in_sizes, int n_in,
                              void* d_out, int out_size, void* d_ws, size_t ws_size,
                              hipStream_t stream) {
    const float* x    = (const float*)d_in[0];
    const float* Wi0  = (const float*)d_in[1];
    const float* bi0  = (const float*)d_in[2];
    const float* Wi1  = (const float*)d_in[3];
    const float* bi1  = (const float*)d_in[4];
    const float* Wi2  = (const float*)d_in[5];
    const float* bi2  = (const float*)d_in[6];
    const float* We0a = (const float*)d_in[7];
    const float* be0a = (const float*)d_in[8];
    const float* We0b = (const float*)d_in[9];
    const float* be0b = (const float*)d_in[10];
    const float* We1a = (const float*)d_in[11];
    const float* be1a = (const float*)d_in[12];
    const float* We1b = (const float*)d_in[13];
    const float* be1b = (const float*)d_in[14];
    const float* Wo0  = (const float*)d_in[15];
    const float* bo0  = (const float*)d_in[16];
    const float* Wo1  = (const float*)d_in[17];
    const float* bo1  = (const float*)d_in[18];
    const float* Wo2  = (const float*)d_in[19];
    const float* bo2  = (const float*)d_in[20];
    float* out = (float*)d_out;

    dgcnn_fused<<<dim3(8192), dim3(64), 0, stream>>>(
        x, Wi0, bi0, Wi1, bi1, Wi2, bi2,
        We0a, be0a, We0b, be0b, We1a, be1a, We1b, be1b,
        Wo0, bo0, Wo1, bo1, Wo2, bo2, out);
}

// Round 4
// 6114.337 us; speedup vs baseline: 3.0824x; 1.0718x over previous
//
#include <hip/hip_runtime.h>
#include <math.h>

#define HH 20
#define HP 21      // padded LDS row stride (doubles / u64)
#define PP 64

// compact expm1 for v<=0: absolute error ~2e-16, result in (-1,0]
__device__ __forceinline__ double expm1_neg(double v) {
    if (v <= -40.0) return -1.0;
    const double LOG2E  = 1.4426950408889634074e+00;
    const double LN2_HI = 6.93147180369123816490e-01;
    const double LN2_LO = 1.90821492927058770002e-10;
    double nd = rint(v * LOG2E);
    double r  = fma(-nd, LN2_HI, v);
    r = fma(-nd, LN2_LO, r);
    double p = 2.08767569878680989792e-09;          // 1/12!
    p = fma(p, r, 2.50521083854417187751e-08);
    p = fma(p, r, 2.75573192239858906526e-07);
    p = fma(p, r, 2.75573192239858925110e-06);
    p = fma(p, r, 2.48015873015873015873e-05);
    p = fma(p, r, 1.98412698412698412698e-04);
    p = fma(p, r, 1.38888888888888888889e-03);
    p = fma(p, r, 8.33333333333333333333e-03);
    p = fma(p, r, 4.16666666666666666667e-02);
    p = fma(p, r, 1.66666666666666666667e-01);
    p = fma(p, r, 5.0e-01);
    p = fma(p, r, 1.0);
    p = fma(p, r, 1.0);
    long long n = (long long)nd;
    double sc = __builtin_bit_cast(double, (unsigned long long)(1023ll + n) << 52);
    return fma(p, sc, -1.0);
}
__device__ __forceinline__ double elu_d(double v) { return v > 0.0 ? v : expm1_neg(v); }
__device__ __forceinline__ float  elu_f(float v)  { return v > 0.0f ? v : expm1f(v); }

// order-preserving double<->u64 encoding for atomicMax
__device__ __forceinline__ unsigned long long fenc64(double f) {
    unsigned long long u = __builtin_bit_cast(unsigned long long, f);
    return (u & 0x8000000000000000ull) ? ~u : (u | 0x8000000000000000ull);
}
__device__ __forceinline__ double fdec64(unsigned long long u) {
    unsigned long long b = (u & 0x8000000000000000ull) ? (u & 0x7fffffffffffffffull) : ~u;
    return __builtin_bit_cast(double, b);
}

__global__ __launch_bounds__(64, 1) void dgcnn_fused(
    const float* __restrict__ x,
    const float* __restrict__ Wi0, const float* __restrict__ bi0,
    const float* __restrict__ Wi1, const float* __restrict__ bi1,
    const float* __restrict__ Wi2, const float* __restrict__ bi2,
    const float* __restrict__ We0a, const float* __restrict__ be0a,
    const float* __restrict__ We0b, const float* __restrict__ be0b,
    const float* __restrict__ We1a, const float* __restrict__ be1a,
    const float* __restrict__ We1b, const float* __restrict__ be1b,
    const float* __restrict__ Wo0, const float* __restrict__ bo0,
    const float* __restrict__ Wo1, const float* __restrict__ bo1,
    const float* __restrict__ Wo2, const float* __restrict__ bo2,
    float* __restrict__ out)
{
    const int b = blockIdx.x;
    const int p = threadIdx.x;

    __shared__ __align__(16) double hbuf[PP][HP];   // 10752 B
    __shared__ double sqv[PP];
    __shared__ int    ivld[PP];
    __shared__ int    cflag[PP];

    // ---------------- input MLP: 3 -> 20 -> 20 -> 20 (f64) ----------------
    double h[HH];
    {
        const size_t xb = (size_t)b * (PP * 3) + (size_t)p * 3;
        const double x0 = (double)x[xb + 0];
        const double x1 = (double)x[xb + 1];
        const double x2 = (double)x[xb + 2];
        double t[HH];
        #pragma unroll
        for (int j = 0; j < HH; ++j)
            t[j] = elu_d(fma(x2, (double)Wi0[2*HH + j],
                         fma(x1, (double)Wi0[HH + j],
                         fma(x0, (double)Wi0[j], (double)bi0[j]))));
        #pragma unroll
        for (int j = 0; j < HH; ++j) h[j] = (double)bi1[j];
        #pragma unroll 2
        for (int d = 0; d < HH; ++d) {
            const double td = t[d];
            #pragma unroll
            for (int j = 0; j < HH; ++j)
                h[j] = fma(td, (double)Wi1[d*HH + j], h[j]);
        }
        #pragma unroll
        for (int j = 0; j < HH; ++j) t[j] = elu_d(h[j]);
        #pragma unroll
        for (int j = 0; j < HH; ++j) h[j] = (double)bi2[j];
        #pragma unroll 2
        for (int d = 0; d < HH; ++d) {
            const double td = t[d];
            #pragma unroll
            for (int j = 0; j < HH; ++j)
                h[j] = fma(td, (double)Wi2[d*HH + j], h[j]);
        }
        #pragma unroll
        for (int j = 0; j < HH; ++j) h[j] = elu_d(h[j]);
    }
    int myvalid = 1;

    // ---------------- two EdgeConv + pool blocks (f64) ----------------
    #pragma unroll 1
    for (int blk = 0; blk < 2; ++blk) {
        const float* Wa = blk ? We1a : We0a;
        const float* ba = blk ? be1a : be0a;
        const float* Wb = blk ? We1b : We0b;
        const float* bb = blk ? be1b : be0b;

        double sqp = 0.0;
        #pragma unroll
        for (int d = 0; d < HH; ++d) sqp = fma(h[d], h[d], sqp);
        #pragma unroll
        for (int j = 0; j < HH; ++j) hbuf[p][j] = h[j];
        sqv[p]  = sqp;
        ivld[p] = myvalid;
        __syncthreads();

        // ---- knn top-4, lexicographic (score, -index), f64 ----
        double s0=-INFINITY, s1=-INFINITY, s2=-INFINITY, s3=-INFINITY;
        int    i0=PP, i1=PP, i2=PP, i3=PP;
        #pragma unroll 2
        for (int q = 0; q < PP; ++q) {
            double dot = 0.0;
            #pragma unroll
            for (int d = 0; d < HH; ++d)
                dot = fma(hbuf[q][d], h[d], dot);
            double s = 2.0*dot - sqp - sqv[q];
            if (q == p || ivld[q] == 0) s = -INFINITY;
            bool b0 = (s > s0) || (s == s0 && q < i0);
            bool b1 = (s > s1) || (s == s1 && q < i1);
            bool b2 = (s > s2) || (s == s2 && q < i2);
            bool b3 = (s > s3) || (s == s3 && q < i3);
            s3 = b2 ? s2 : (b3 ? s : s3);  i3 = b2 ? i2 : (b3 ? q : i3);
            s2 = b1 ? s1 : (b2 ? s : s2);  i2 = b1 ? i1 : (b2 ? q : i2);
            s1 = b0 ? s0 : (b1 ? s : s1);  i1 = b0 ? i0 : (b1 ? q : i1);
            s0 = b0 ? s  : s0;             i0 = b0 ? q  : i0;
        }

        // ---- EdgeConv: base folds the xi contribution of layer A ----
        double base[HH];
        #pragma unroll
        for (int j = 0; j < HH; ++j) base[j] = (double)ba[j];
        #pragma unroll 2
        for (int d = 0; d < HH; ++d) {
            const double hd = h[d];
            #pragma unroll
            for (int j = 0; j < HH; ++j) {
                const double wd = (double)Wa[d*HH + j] - (double)Wa[(HH + d)*HH + j];
                base[j] = fma(hd, wd, base[j]);
            }
        }
        double hsum[HH];
        #pragma unroll
        for (int j = 0; j < HH; ++j) hsum[j] = 0.0;

        #pragma unroll 1
        for (int k = 0; k < 4; ++k) {      // one neighbor at a time (register budget)
            const int jn = (k == 0) ? i0 : (k == 1) ? i1 : (k == 2) ? i2 : i3;
            const double vn = (double)ivld[jn];

            double m1[HH];
            #pragma unroll
            for (int j = 0; j < HH; ++j) m1[j] = base[j];
            #pragma unroll 2
            for (int d = 0; d < HH; ++d) {
                const double qd = hbuf[jn][d];
                #pragma unroll
                for (int j = 0; j < HH; ++j)
                    m1[j] = fma(qd, (double)Wa[(HH + d)*HH + j], m1[j]);
            }
            #pragma unroll
            for (int j = 0; j < HH; ++j) m1[j] = elu_d(m1[j]);

            #pragma unroll
            for (int j = 0; j < HH; ++j) {
                double a0 = (double)bb[j];
                #pragma unroll
                for (int d = 0; d < HH; ++d)
                    a0 = fma(m1[d], (double)Wb[d*HH + j], a0);
                hsum[j] = fma(elu_d(a0), vn, hsum[j]);
            }
        }
        {
            const double vpd = (double)myvalid;
            #pragma unroll
            for (int j = 0; j < HH; ++j) hsum[j] *= vpd;
        }
        __syncthreads();   // all lanes done reading hbuf

        // ---- pool: cluster = min(p, nn0), scatter-max (u64-encoded f64) ----
        unsigned long long* pbuf = (unsigned long long*)&hbuf[0][0];
        #pragma unroll
        for (int j = 0; j < HH; ++j) pbuf[p*HP + j] = 0ull;  // < fenc64(anything)
        cflag[p] = 0;
        __syncthreads();
        {
            const int c = min(p, i0);
            if (myvalid) {
                cflag[c] = 1;                       // benign same-value race
                #pragma unroll
                for (int j = 0; j < HH; ++j)
                    atomicMax(&pbuf[c*HP + j], fenc64(hsum[j]));
            }
        }
        __syncthreads();
        {
            const int nv = cflag[p];
            myvalid = nv;
            #pragma unroll
            for (int j = 0; j < HH; ++j)
                h[j] = nv ? fdec64(pbuf[p*HP + j]) : 0.0;
        }
        __syncthreads();
    }

    // ---------------- continuous tail in f32 ----------------
    float hf[HH];
    #pragma unroll
    for (int j = 0; j < HH; ++j) hf[j] = myvalid ? (float)h[j] : -INFINITY;
    #pragma unroll
    for (int s = 1; s < 64; s <<= 1) {
        #pragma unroll
        for (int j = 0; j < HH; ++j)
            hf[j] = fmaxf(hf[j], __shfl_xor(hf[j], s));
    }

    float o1[HH], o2[HH], lg[10];
    #pragma unroll
    for (int j = 0; j < HH; ++j) o1[j] = bo0[j];
    #pragma unroll 2
    for (int d = 0; d < HH; ++d) {
        #pragma unroll
        for (int j = 0; j < HH; ++j) o1[j] = fmaf(hf[d], Wo0[d*HH + j], o1[j]);
    }
    #pragma unroll
    for (int j = 0; j < HH; ++j) o1[j] = elu_f(o1[j]);
    #pragma unroll
    for (int j = 0; j < HH; ++j) o2[j] = bo1[j];
    #pragma unroll 2
    for (int d = 0; d < HH; ++d) {
        #pragma unroll
        for (int j = 0; j < HH; ++j) o2[j] = fmaf(o1[d], Wo1[d*HH + j], o2[j]);
    }
    #pragma unroll
    for (int j = 0; j < HH; ++j) o2[j] = elu_f(o2[j]);
    #pragma unroll
    for (int j = 0; j < 10; ++j) lg[j] = bo2[j];
    #pragma unroll 2
    for (int d = 0; d < HH; ++d) {
        #pragma unroll
        for (int j = 0; j < 10; ++j) lg[j] = fmaf(o2[d], Wo2[d*10 + j], lg[j]);
    }
    float m = lg[0];
    #pragma unroll
    for (int j = 1; j < 10; ++j) m = fmaxf(m, lg[j]);
    float ssum = 0.0f;
    #pragma unroll
    for (int j = 0; j < 10; ++j) ssum += expf(lg[j] - m);
    const float lse = m + logf(ssum);
    if (p < 10) {
        float v = 0.0f;
        #pragma unroll
        for (int j = 0; j < 10; ++j) v = (p == j) ? lg[j] : v;
        out[(size_t)b * 10 + p] = v - lse;
    }
}

extern "C" void kernel_launch(void* const* d_in, const int* in_sizes, int n_in,
                              void* d_out, int out_size, void* d_ws, size_t ws_size,
                              hipStream_t stream) {
    const float* x    = (const float*)d_in[0];
    const float* Wi0  = (const float*)d_in[1];
    const float* bi0  = (const float*)d_in[2];
    const float* Wi1  = (const float*)d_in[3];
    const float* bi1  = (const float*)d_in[4];
    const float* Wi2  = (const float*)d_in[5];
    const float* bi2  = (const float*)d_in[6];
    const float* We0a = (const float*)d_in[7];
    const float* be0a = (const float*)d_in[8];
    const float* We0b = (const float*)d_in[9];
    const float* be0b = (const float*)d_in[10];
    const float* We1a = (const float*)d_in[11];
    const float* be1a = (const float*)d_in[12];
    const float* We1b = (const float*)d_in[13];
    const float* be1b = (const float*)d_in[14];
    const float* Wo0  = (const float*)d_in[15];
    const float* bo0  = (const float*)d_in[16];
    const float* Wo1  = (const float*)d_in[17];
    const float* bo1  = (const float*)d_in[18];
    const float* Wo2  = (const float*)d_in[19];
    const float* bo2  = (const float*)d_in[20];
    float* out = (float*)d_out;

    dgcnn_fused<<<dim3(8192), dim3(64), 0, stream>>>(
        x, Wi0, bi0, Wi1, bi1, Wi2, bi2,
        We0a, be0a, We0b, be0b, We1a, be1a, We1b, be1b,
        Wo0, bo0, Wo1, bo1, Wo2, bo2, out);
}

// Round 5
// 1885.975 us; speedup vs baseline: 9.9931x; 3.2420x over previous
//
#include <hip/hip_runtime.h>
#include <math.h>

#define HH 20
#define HP 21      // padded LDS row stride (doubles / u64)
#define PP 64

// ---- f64 weight workspace layout (doubles) ----
#define W_WI0 0      // 60
#define W_BI0 60     // 20
#define W_WI1 80     // 400
#define W_BI1 480    // 20
#define W_WI2 500    // 400
#define W_BI2 900    // 20
#define W_AH0 920    // 400  We0a rows 20..39 (xj part)
#define W_BA0 1320   // 20
#define W_WB0 1340   // 400
#define W_BB0 1740   // 20
#define W_AH1 1760   // 400
#define W_BA1 2160   // 20
#define W_WB1 2180   // 400
#define W_BB1 2580   // 20
#define W_AD0 2600   // 400  We0a[d] - We0a[20+d]  (xi-fold diff)
#define W_AD1 3000   // 400
#define W_TOT 3400

// compact expm1 for v<=0: absolute error ~2e-16, result in (-1,0]
__device__ __forceinline__ double expm1_neg(double v) {
    if (v <= -40.0) return -1.0;
    const double LOG2E  = 1.4426950408889634074e+00;
    const double LN2_HI = 6.93147180369123816490e-01;
    const double LN2_LO = 1.90821492927058770002e-10;
    double nd = rint(v * LOG2E);
    double r  = fma(-nd, LN2_HI, v);
    r = fma(-nd, LN2_LO, r);
    double p = 2.08767569878680989792e-09;          // 1/12!
    p = fma(p, r, 2.50521083854417187751e-08);
    p = fma(p, r, 2.75573192239858906526e-07);
    p = fma(p, r, 2.75573192239858925110e-06);
    p = fma(p, r, 2.48015873015873015873e-05);
    p = fma(p, r, 1.98412698412698412698e-04);
    p = fma(p, r, 1.38888888888888888889e-03);
    p = fma(p, r, 8.33333333333333333333e-03);
    p = fma(p, r, 4.16666666666666666667e-02);
    p = fma(p, r, 1.66666666666666666667e-01);
    p = fma(p, r, 5.0e-01);
    p = fma(p, r, 1.0);
    p = fma(p, r, 1.0);
    long long n = (long long)nd;
    double sc = __builtin_bit_cast(double, (unsigned long long)(1023ll + n) << 52);
    return fma(p, sc, -1.0);
}
__device__ __forceinline__ double elu_d(double v) { return v > 0.0 ? v : expm1_neg(v); }
__device__ __forceinline__ float  elu_f(float v)  { return v > 0.0f ? v : expm1f(v); }

// order-preserving double<->u64 encoding for atomicMax
__device__ __forceinline__ unsigned long long fenc64(double f) {
    unsigned long long u = __builtin_bit_cast(unsigned long long, f);
    return (u & 0x8000000000000000ull) ? ~u : (u | 0x8000000000000000ull);
}
__device__ __forceinline__ double fdec64(unsigned long long u) {
    unsigned long long b = (u & 0x8000000000000000ull) ? (u & 0x7fffffffffffffffull) : ~u;
    return __builtin_bit_cast(double, b);
}

__global__ __launch_bounds__(256) void prep_weights(
    const float* __restrict__ Wi0, const float* __restrict__ bi0,
    const float* __restrict__ Wi1, const float* __restrict__ bi1,
    const float* __restrict__ Wi2, const float* __restrict__ bi2,
    const float* __restrict__ We0a, const float* __restrict__ be0a,
    const float* __restrict__ We0b, const float* __restrict__ be0b,
    const float* __restrict__ We1a, const float* __restrict__ be1a,
    const float* __restrict__ We1b, const float* __restrict__ be1b,
    double* __restrict__ ws)
{
    const int t = threadIdx.x;
    #define CV(off, src, n) for (int i = t; i < (n); i += 256) ws[(off) + i] = (double)(src)[i];
    CV(W_WI0, Wi0, 60)  CV(W_BI0, bi0, 20)
    CV(W_WI1, Wi1, 400) CV(W_BI1, bi1, 20)
    CV(W_WI2, Wi2, 400) CV(W_BI2, bi2, 20)
    CV(W_AH0, We0a + 400, 400) CV(W_BA0, be0a, 20)
    CV(W_WB0, We0b, 400)       CV(W_BB0, be0b, 20)
    CV(W_AH1, We1a + 400, 400) CV(W_BA1, be1a, 20)
    CV(W_WB1, We1b, 400)       CV(W_BB1, be1b, 20)
    for (int i = t; i < 400; i += 256) ws[W_AD0 + i] = (double)We0a[i] - (double)We0a[400 + i];
    for (int i = t; i < 400; i += 256) ws[W_AD1 + i] = (double)We1a[i] - (double)We1a[400 + i];
    #undef CV
}

#define SBAR() __builtin_amdgcn_sched_barrier(0)

__global__ __launch_bounds__(64, 1) void dgcnn_fused(
    const float* __restrict__ x,
    const double* __restrict__ wd,
    const float* __restrict__ Wo0, const float* __restrict__ bo0,
    const float* __restrict__ Wo1, const float* __restrict__ bo1,
    const float* __restrict__ Wo2, const float* __restrict__ bo2,
    float* __restrict__ out)
{
    const int b = blockIdx.x;
    const int p = threadIdx.x;

    __shared__ __align__(16) double hbuf[PP][HP];   // 10752 B
    __shared__ double sqv[PP];
    __shared__ int    ivld[PP];
    __shared__ int    cflag[PP];

    // ---------------- input MLP: 3 -> 20 -> 20 -> 20 (f64) ----------------
    double h[HH];
    {
        const size_t xb = (size_t)b * (PP * 3) + (size_t)p * 3;
        const double x0 = (double)x[xb + 0];
        const double x1 = (double)x[xb + 1];
        const double x2 = (double)x[xb + 2];
        double t[HH];
        #pragma unroll
        for (int j = 0; j < HH; ++j)
            t[j] = fma(x2, wd[W_WI0 + 2*HH + j],
                   fma(x1, wd[W_WI0 + HH + j],
                   fma(x0, wd[W_WI0 + j], wd[W_BI0 + j])));
        #pragma unroll
        for (int j5 = 0; j5 < HH; j5 += 5) {
            #pragma unroll
            for (int j = j5; j < j5 + 5; ++j) t[j] = elu_d(t[j]);
            SBAR();
        }
        #pragma unroll
        for (int j = 0; j < HH; ++j) h[j] = wd[W_BI1 + j];
        #pragma unroll 2
        for (int d = 0; d < HH; ++d) {
            const double td = t[d];
            #pragma unroll
            for (int j = 0; j < HH; ++j)
                h[j] = fma(td, wd[W_WI1 + d*HH + j], h[j]);
        }
        #pragma unroll
        for (int j5 = 0; j5 < HH; j5 += 5) {
            #pragma unroll
            for (int j = j5; j < j5 + 5; ++j) t[j] = elu_d(h[j]);
            SBAR();
        }
        #pragma unroll
        for (int j = 0; j < HH; ++j) h[j] = wd[W_BI2 + j];
        #pragma unroll 2
        for (int d = 0; d < HH; ++d) {
            const double td = t[d];
            #pragma unroll
            for (int j = 0; j < HH; ++j)
                h[j] = fma(td, wd[W_WI2 + d*HH + j], h[j]);
        }
        #pragma unroll
        for (int j5 = 0; j5 < HH; j5 += 5) {
            #pragma unroll
            for (int j = j5; j < j5 + 5; ++j) h[j] = elu_d(h[j]);
            SBAR();
        }
    }
    int myvalid = 1;

    // ---------------- two EdgeConv + pool blocks (f64) ----------------
    #pragma unroll 1
    for (int blk = 0; blk < 2; ++blk) {
        const double* WaH = wd + (blk ? W_AH1 : W_AH0);
        const double* WaD = wd + (blk ? W_AD1 : W_AD0);
        const double* Wb  = wd + (blk ? W_WB1 : W_WB0);
        const double* ba  = wd + (blk ? W_BA1 : W_BA0);
        const double* bb  = wd + (blk ? W_BB1 : W_BB0);

        double sqp = 0.0;
        #pragma unroll
        for (int d = 0; d < HH; ++d) sqp = fma(h[d], h[d], sqp);
        #pragma unroll
        for (int j = 0; j < HH; ++j) hbuf[p][j] = h[j];
        sqv[p]  = sqp;
        ivld[p] = myvalid;
        __syncthreads();

        // ---- knn top-4, lexicographic (score, -index), f64 ----
        double s0=-INFINITY, s1=-INFINITY, s2=-INFINITY, s3=-INFINITY;
        int    i0=PP, i1=PP, i2=PP, i3=PP;
        #pragma unroll 2
        for (int q = 0; q < PP; ++q) {
            double dot = 0.0;
            #pragma unroll
            for (int d = 0; d < HH; ++d)
                dot = fma(hbuf[q][d], h[d], dot);
            double s = 2.0*dot - sqp - sqv[q];
            if (q == p || ivld[q] == 0) s = -INFINITY;
            bool b0 = (s > s0) || (s == s0 && q < i0);
            bool b1 = (s > s1) || (s == s1 && q < i1);
            bool b2 = (s > s2) || (s == s2 && q < i2);
            bool b3 = (s > s3) || (s == s3 && q < i3);
            s3 = b2 ? s2 : (b3 ? s : s3);  i3 = b2 ? i2 : (b3 ? q : i3);
            s2 = b1 ? s1 : (b2 ? s : s2);  i2 = b1 ? i1 : (b2 ? q : i2);
            s1 = b0 ? s0 : (b1 ? s : s1);  i1 = b0 ? i0 : (b1 ? q : i1);
            s0 = b0 ? s  : s0;             i0 = b0 ? q  : i0;
        }
        SBAR();

        // ---- EdgeConv: base folds the xi contribution of layer A ----
        double base[HH];
        #pragma unroll
        for (int j = 0; j < HH; ++j) base[j] = ba[j];
        #pragma unroll 2
        for (int d = 0; d < HH; ++d) {
            const double hd = h[d];
            #pragma unroll
            for (int j = 0; j < HH; ++j)
                base[j] = fma(hd, WaD[d*HH + j], base[j]);
        }
        double hsum[HH];
        #pragma unroll
        for (int j = 0; j < HH; ++j) hsum[j] = 0.0;
        SBAR();

        #pragma unroll 1
        for (int k = 0; k < 4; ++k) {      // one neighbor at a time (register budget)
            const int jn = (k == 0) ? i0 : (k == 1) ? i1 : (k == 2) ? i2 : i3;
            const double vn = (double)ivld[jn];

            double m1[HH];
            #pragma unroll
            for (int j = 0; j < HH; ++j) m1[j] = base[j];
            #pragma unroll 2
            for (int d = 0; d < HH; ++d) {
                const double qd = hbuf[jn][d];
                #pragma unroll
                for (int j = 0; j < HH; ++j)
                    m1[j] = fma(qd, WaH[d*HH + j], m1[j]);
            }
            #pragma unroll
            for (int j5 = 0; j5 < HH; j5 += 5) {
                #pragma unroll
                for (int j = j5; j < j5 + 5; ++j) m1[j] = elu_d(m1[j]);
                SBAR();
            }

            #pragma unroll
            for (int j5 = 0; j5 < HH; j5 += 5) {
                #pragma unroll
                for (int j = j5; j < j5 + 5; ++j) {
                    double a0 = bb[j];
                    #pragma unroll
                    for (int d = 0; d < HH; ++d)
                        a0 = fma(m1[d], Wb[d*HH + j], a0);
                    hsum[j] = fma(elu_d(a0), vn, hsum[j]);
                }
                SBAR();
            }
        }
        {
            const double vpd = (double)myvalid;
            #pragma unroll
            for (int j = 0; j < HH; ++j) hsum[j] *= vpd;
        }
        __syncthreads();   // all lanes done reading hbuf

        // ---- pool: cluster = min(p, nn0), scatter-max (u64-encoded f64) ----
        unsigned long long* pbuf = (unsigned long long*)&hbuf[0][0];
        #pragma unroll
        for (int j = 0; j < HH; ++j) pbuf[p*HP + j] = 0ull;  // < fenc64(anything)
        cflag[p] = 0;
        __syncthreads();
        {
            const int c = min(p, i0);
            if (myvalid) {
                cflag[c] = 1;                       // benign same-value race
                #pragma unroll
                for (int j = 0; j < HH; ++j)
                    atomicMax(&pbuf[c*HP + j], fenc64(hsum[j]));
            }
        }
        __syncthreads();
        {
            const int nv = cflag[p];
            myvalid = nv;
            #pragma unroll
            for (int j = 0; j < HH; ++j)
                h[j] = nv ? fdec64(pbuf[p*HP + j]) : 0.0;
        }
        __syncthreads();
    }

    // ---------------- continuous tail in f32 ----------------
    float hf[HH];
    #pragma unroll
    for (int j = 0; j < HH; ++j) hf[j] = myvalid ? (float)h[j] : -INFINITY;
    #pragma unroll
    for (int s = 1; s < 64; s <<= 1) {
        #pragma unroll
        for (int j = 0; j < HH; ++j)
            hf[j] = fmaxf(hf[j], __shfl_xor(hf[j], s));
    }

    float o1[HH], o2[HH], lg[10];
    #pragma unroll
    for (int j = 0; j < HH; ++j) o1[j] = bo0[j];
    #pragma unroll 2
    for (int d = 0; d < HH; ++d) {
        #pragma unroll
        for (int j = 0; j < HH; ++j) o1[j] = fmaf(hf[d], Wo0[d*HH + j], o1[j]);
    }
    #pragma unroll
    for (int j = 0; j < HH; ++j) o1[j] = elu_f(o1[j]);
    #pragma unroll
    for (int j = 0; j < HH; ++j) o2[j] = bo1[j];
    #pragma unroll 2
    for (int d = 0; d < HH; ++d) {
        #pragma unroll
        for (int j = 0; j < HH; ++j) o2[j] = fmaf(o1[d], Wo1[d*HH + j], o2[j]);
    }
    #pragma unroll
    for (int j = 0; j < HH; ++j) o2[j] = elu_f(o2[j]);
    #pragma unroll
    for (int j = 0; j < 10; ++j) lg[j] = bo2[j];
    #pragma unroll 2
    for (int d = 0; d < HH; ++d) {
        #pragma unroll
        for (int j = 0; j < 10; ++j) lg[j] = fmaf(o2[d], Wo2[d*10 + j], lg[j]);
    }
    float m = lg[0];
    #pragma unroll
    for (int j = 1; j < 10; ++j) m = fmaxf(m, lg[j]);
    float ssum = 0.0f;
    #pragma unroll
    for (int j = 0; j < 10; ++j) ssum += expf(lg[j] - m);
    const float lse = m + logf(ssum);
    if (p < 10) {
        float v = 0.0f;
        #pragma unroll
        for (int j = 0; j < 10; ++j) v = (p == j) ? lg[j] : v;
        out[(size_t)b * 10 + p] = v - lse;
    }
}

extern "C" void kernel_launch(void* const* d_in, const int* in_sizes, int n_in,
                              void* d_out, int out_size, void* d_ws, size_t ws_size,
                              hipStream_t stream) {
    const float* x    = (const float*)d_in[0];
    const float* Wi0  = (const float*)d_in[1];
    const float* bi0  = (const float*)d_in[2];
    const float* Wi1  = (const float*)d_in[3];
    const float* bi1  = (const float*)d_in[4];
    const float* Wi2  = (const float*)d_in[5];
    const float* bi2  = (const float*)d_in[6];
    const float* We0a = (const float*)d_in[7];
    const float* be0a = (const float*)d_in[8];
    const float* We0b = (const float*)d_in[9];
    const float* be0b = (const float*)d_in[10];
    const float* We1a = (const float*)d_in[11];
    const float* be1a = (const float*)d_in[12];
    const float* We1b = (const float*)d_in[13];
    const float* be1b = (const float*)d_in[14];
    const float* Wo0  = (const float*)d_in[15];
    const float* bo0  = (const float*)d_in[16];
    const float* Wo1  = (const float*)d_in[17];
    const float* bo1  = (const float*)d_in[18];
    const float* Wo2  = (const float*)d_in[19];
    const float* bo2  = (const float*)d_in[20];
    float* out = (float*)d_out;
    double* ws = (double*)d_ws;

    prep_weights<<<dim3(1), dim3(256), 0, stream>>>(
        Wi0, bi0, Wi1, bi1, Wi2, bi2,
        We0a, be0a, We0b, be0b, We1a, be1a, We1b, be1b, ws);

    dgcnn_fused<<<dim3(8192), dim3(64), 0, stream>>>(
        x, ws, Wo0, bo0, Wo1, bo1, Wo2, bo2, out);
}

// Round 7
// 849.679 us; speedup vs baseline: 22.1810x; 2.2196x over previous
//
#include <hip/hip_runtime.h>
#include <math.h>

#define HH 20
#define HP 21      // padded LDS row stride (doubles / u64)
#define PP 64

// ---- f64 weight workspace layout (doubles) ----
#define W_WI0 0      // 60
#define W_BI0 60     // 20
#define W_WI1 80     // 400
#define W_BI1 480    // 20
#define W_WI2 500    // 400
#define W_BI2 900    // 20
#define W_EB0 920    // blk0 bundle: WaD 0..399 | WaH 400..799 | Wb 800..1199 | ba 1200..1219 | bb 1220..1239
#define W_EB1 2160   // blk1 bundle
#define W_TOT 3400

// compact expm1 for v<=0: rel error ~7e-12, result in (-1,0]
__device__ __forceinline__ double expm1_neg(double v) {
    if (v <= -40.0) return -1.0;
    const double LOG2E  = 1.4426950408889634074e+00;
    const double LN2_HI = 6.93147180369123816490e-01;
    const double LN2_LO = 1.90821492927058770002e-10;
    double nd = rint(v * LOG2E);
    double r  = fma(-nd, LN2_HI, v);
    r = fma(-nd, LN2_LO, r);
    double p = 2.75573192239858925110e-06;          // 1/9!
    p = fma(p, r, 2.48015873015873015873e-05);      // 1/8!
    p = fma(p, r, 1.98412698412698412698e-04);      // 1/7!
    p = fma(p, r, 1.38888888888888888889e-03);      // 1/6!
    p = fma(p, r, 8.33333333333333333333e-03);      // 1/5!
    p = fma(p, r, 4.16666666666666666667e-02);      // 1/4!
    p = fma(p, r, 1.66666666666666666667e-01);      // 1/3!
    p = fma(p, r, 5.0e-01);                         // 1/2!
    p = fma(p, r, 1.0);
    p = fma(p, r, 1.0);
    long long n = (long long)nd;
    double sc = __builtin_bit_cast(double, (unsigned long long)(1023ll + n) << 52);
    return fma(p, sc, -1.0);
}
__device__ __forceinline__ double elu_d(double v) { return v > 0.0 ? v : expm1_neg(v); }
__device__ __forceinline__ float  elu_f(float v)  { return v > 0.0f ? v : expm1f(v); }

// order-preserving double<->u64 encoding
__device__ __forceinline__ unsigned long long fenc64(double f) {
    unsigned long long u = __builtin_bit_cast(unsigned long long, f);
    return (u & 0x8000000000000000ull) ? ~u : (u | 0x8000000000000000ull);
}
__device__ __forceinline__ double fdec64(unsigned long long u) {
    unsigned long long b = (u & 0x8000000000000000ull) ? (u & 0x7fffffffffffffffull) : ~u;
    return __builtin_bit_cast(double, b);
}

__global__ __launch_bounds__(256) void prep_weights(
    const float* __restrict__ Wi0, const float* __restrict__ bi0,
    const float* __restrict__ Wi1, const float* __restrict__ bi1,
    const float* __restrict__ Wi2, const float* __restrict__ bi2,
    const float* __restrict__ We0a, const float* __restrict__ be0a,
    const float* __restrict__ We0b, const float* __restrict__ be0b,
    const float* __restrict__ We1a, const float* __restrict__ be1a,
    const float* __restrict__ We1b, const float* __restrict__ be1b,
    double* __restrict__ ws)
{
    const int t = threadIdx.x;
    #define CV(off, src, n) for (int i = t; i < (n); i += 256) ws[(off) + i] = (double)(src)[i];
    CV(W_WI0, Wi0, 60)  CV(W_BI0, bi0, 20)
    CV(W_WI1, Wi1, 400) CV(W_BI1, bi1, 20)
    CV(W_WI2, Wi2, 400) CV(W_BI2, bi2, 20)
    for (int i = t; i < 400; i += 256) {
        ws[W_EB0 +       i] = (double)We0a[i] - (double)We0a[400 + i];
        ws[W_EB0 + 400 + i] = (double)We0a[400 + i];
        ws[W_EB0 + 800 + i] = (double)We0b[i];
        ws[W_EB1 +       i] = (double)We1a[i] - (double)We1a[400 + i];
        ws[W_EB1 + 400 + i] = (double)We1a[400 + i];
        ws[W_EB1 + 800 + i] = (double)We1b[i];
    }
    for (int i = t; i < 20; i += 256) {
        ws[W_EB0 + 1200 + i] = (double)be0a[i];
        ws[W_EB0 + 1220 + i] = (double)be0b[i];
        ws[W_EB1 + 1200 + i] = (double)be1a[i];
        ws[W_EB1 + 1220 + i] = (double)be1b[i];
    }
    #undef CV
}

#define SBAR() __builtin_amdgcn_sched_barrier(0)

__global__ __launch_bounds__(64, 1) void dgcnn_fused(
    const float* __restrict__ x,
    const double* __restrict__ wd,
    const float* __restrict__ Wo0, const float* __restrict__ bo0,
    const float* __restrict__ Wo1, const float* __restrict__ bo1,
    const float* __restrict__ Wo2, const float* __restrict__ bo2,
    float* __restrict__ out)
{
    const int b = blockIdx.x;
    const int p = threadIdx.x;

    __shared__ __align__(16) double hbuf[PP][HP];   // h rows (+sq in pad), then y rows, then pool buf
    __shared__ __align__(16) double wlds[1280];     // this blk's edgeconv weights (1240 used, 40 pad)
    __shared__ int ivld[PP];
    __shared__ int cflag[PP];

    // ---------------- input MLP: 3 -> 20 -> 20 -> 20 (f64, s_load weights) ----------------
    double h[HH];
    {
        const size_t xb = (size_t)b * (PP * 3) + (size_t)p * 3;
        const double x0 = (double)x[xb + 0];
        const double x1 = (double)x[xb + 1];
        const double x2 = (double)x[xb + 2];
        double t[HH];
        #pragma unroll
        for (int j = 0; j < HH; ++j)
            t[j] = fma(x2, wd[W_WI0 + 2*HH + j],
                   fma(x1, wd[W_WI0 + HH + j],
                   fma(x0, wd[W_WI0 + j], wd[W_BI0 + j])));
        #pragma unroll
        for (int j5 = 0; j5 < HH; j5 += 5) {
            #pragma unroll
            for (int j = j5; j < j5 + 5; ++j) t[j] = elu_d(t[j]);
            SBAR();
        }
        #pragma unroll
        for (int j = 0; j < HH; ++j) h[j] = wd[W_BI1 + j];
        #pragma unroll 2
        for (int d = 0; d < HH; ++d) {
            const double td = t[d];
            #pragma unroll
            for (int j = 0; j < HH; ++j)
                h[j] = fma(td, wd[W_WI1 + d*HH + j], h[j]);
        }
        #pragma unroll
        for (int j5 = 0; j5 < HH; j5 += 5) {
            #pragma unroll
            for (int j = j5; j < j5 + 5; ++j) t[j] = elu_d(h[j]);
            SBAR();
        }
        #pragma unroll
        for (int j = 0; j < HH; ++j) h[j] = wd[W_BI2 + j];
        #pragma unroll 2
        for (int d = 0; d < HH; ++d) {
            const double td = t[d];
            #pragma unroll
            for (int j = 0; j < HH; ++j)
                h[j] = fma(td, wd[W_WI2 + d*HH + j], h[j]);
        }
        #pragma unroll
        for (int j5 = 0; j5 < HH; j5 += 5) {
            #pragma unroll
            for (int j = j5; j < j5 + 5; ++j) h[j] = elu_d(h[j]);
            SBAR();
        }
    }
    int myvalid = 1;

    // ---------------- two EdgeConv + pool blocks (f64) ----------------
    #pragma unroll 1
    for (int blk = 0; blk < 2; ++blk) {
        const double* bundle = wd + (blk ? W_EB1 : W_EB0);
        // cooperative stage of this blk's weights into LDS (coalesced, guarded tail)
        #pragma unroll
        for (int i = 0; i < 20; ++i) {
            const int idx = i * 64 + p;
            wlds[idx] = (idx < 1240) ? bundle[idx] : 0.0;
        }

        double sqp = 0.0;
        #pragma unroll
        for (int d = 0; d < HH; ++d) sqp = fma(h[d], h[d], sqp);
        #pragma unroll
        for (int j = 0; j < HH; ++j) hbuf[p][j] = h[j];
        hbuf[p][HH] = sqp;                          // sq in pad slot
        ivld[p] = myvalid;
        __syncthreads();

        // ---- knn top-4: enc = (fenc64(s) & ~63) | (63-q), single u64 sort key ----
        unsigned long long e0 = 0ull, e1 = 0ull, e2 = 0ull, e3 = 0ull;
        #pragma unroll 2
        for (int q = 0; q < PP; ++q) {
            double dot = 0.0;
            #pragma unroll
            for (int d = 0; d < HH; ++d)
                dot = fma(hbuf[q][d], h[d], dot);
            double s = 2.0*dot - sqp - hbuf[q][HH];
            if (q == p || ivld[q] == 0) s = -INFINITY;
            const unsigned long long e =
                (fenc64(s) & ~63ull) | (unsigned long long)(63 - q);
            const bool b0 = e > e0;
            const bool b1 = e > e1;
            const bool b2 = e > e2;
            const bool b3 = e > e3;
            e3 = b2 ? e2 : (b3 ? e : e3);
            e2 = b1 ? e1 : (b2 ? e : e2);
            e1 = b0 ? e0 : (b1 ? e : e1);
            e0 = b0 ? e  : e0;
        }
        SBAR();
        const int i0 = 63 - (int)(e0 & 63ull);

        // ---- base[j] = ba[j] + sum_d h[d] * (Wa_xi - Wa_xj)[d][j]  (LDS weights) ----
        double base[HH];
        #pragma unroll
        for (int j = 0; j < HH; ++j) base[j] = wlds[1200 + j];
        #pragma unroll 2
        for (int d = 0; d < HH; ++d) {
            const double hd = h[d];
            #pragma unroll
            for (int j = 0; j < HH; ++j)
                base[j] = fma(hd, wlds[d*HH + j], base[j]);
        }
        // ---- y[j] = sum_d h[d] * Wa_xj[d][j]; share across edges via hbuf ----
        double y[HH];
        #pragma unroll
        for (int j = 0; j < HH; ++j) y[j] = 0.0;
        #pragma unroll 2
        for (int d = 0; d < HH; ++d) {
            const double hd = h[d];
            #pragma unroll
            for (int j = 0; j < HH; ++j)
                y[j] = fma(hd, wlds[400 + d*HH + j], y[j]);
        }
        __syncthreads();   // everyone done reading h rows of hbuf
        #pragma unroll
        for (int j = 0; j < HH; ++j) hbuf[p][j] = y[j];
        __syncthreads();

        double hsum[HH];
        #pragma unroll
        for (int j = 0; j < HH; ++j) hsum[j] = 0.0;

        #pragma unroll 1
        for (int k = 0; k < 4; ++k) {
            const unsigned long long ek = (k == 0) ? e0 : (k == 1) ? e1 : (k == 2) ? e2 : e3;
            const int jn = 63 - (int)(ek & 63ull);
            const double vn = (double)ivld[jn];

            double m1[HH];
            #pragma unroll
            for (int j = 0; j < HH; ++j) m1[j] = base[j] + hbuf[jn][j];
            #pragma unroll
            for (int j5 = 0; j5 < HH; j5 += 5) {
                #pragma unroll
                for (int j = j5; j < j5 + 5; ++j) m1[j] = elu_d(m1[j]);
                SBAR();
            }

            #pragma unroll
            for (int j5 = 0; j5 < HH; j5 += 5) {
                #pragma unroll
                for (int j = j5; j < j5 + 5; ++j) {
                    double a0 = wlds[1220 + j];
                    #pragma unroll
                    for (int d = 0; d < HH; ++d)
                        a0 = fma(m1[d], wlds[800 + d*HH + j], a0);
                    hsum[j] = fma(elu_d(a0), vn, hsum[j]);
                }
                SBAR();
            }
        }
        {
            const double vpd = (double)myvalid;
            #pragma unroll
            for (int j = 0; j < HH; ++j) hsum[j] *= vpd;
        }
        __syncthreads();   // all lanes done reading y rows of hbuf

        // ---- pool: cluster = min(p, nn0), scatter-max (u64-encoded f64) ----
        unsigned long long* pbuf = (unsigned long long*)&hbuf[0][0];
        #pragma unroll
        for (int j = 0; j < HH; ++j) pbuf[p*HP + j] = 0ull;  // < fenc64(anything)
        cflag[p] = 0;
        __syncthreads();
        {
            const int c = min(p, i0);
            if (myvalid) {
                cflag[c] = 1;                       // benign same-value race
                #pragma unroll
                for (int j = 0; j < HH; ++j)
                    atomicMax(&pbuf[c*HP + j], fenc64(hsum[j]));
            }
        }
        __syncthreads();
        {
            const int nv = cflag[p];
            myvalid = nv;
            #pragma unroll
            for (int j = 0; j < HH; ++j)
                h[j] = nv ? fdec64(pbuf[p*HP + j]) : 0.0;
        }
        __syncthreads();
    }

    // ---------------- continuous tail in f32 ----------------
    float hf[HH];
    #pragma unroll
    for (int j = 0; j < HH; ++j) hf[j] = myvalid ? (float)h[j] : -INFINITY;
    #pragma unroll
    for (int s = 1; s < 64; s <<= 1) {
        #pragma unroll
        for (int j = 0; j < HH; ++j)
            hf[j] = fmaxf(hf[j], __shfl_xor(hf[j], s));
    }

    float o1[HH], o2[HH], lg[10];
    #pragma unroll
    for (int j = 0; j < HH; ++j) o1[j] = bo0[j];
    #pragma unroll 2
    for (int d = 0; d < HH; ++d) {
        #pragma unroll
        for (int j = 0; j < HH; ++j) o1[j] = fmaf(hf[d], Wo0[d*HH + j], o1[j]);
    }
    #pragma unroll
    for (int j = 0; j < HH; ++j) o1[j] = elu_f(o1[j]);
    #pragma unroll
    for (int j = 0; j < HH; ++j) o2[j] = bo1[j];
    #pragma unroll 2
    for (int d = 0; d < HH; ++d) {
        #pragma unroll
        for (int j = 0; j < HH; ++j) o2[j] = fmaf(o1[d], Wo1[d*HH + j], o2[j]);
    }
    #pragma unroll
    for (int j = 0; j < HH; ++j) o2[j] = elu_f(o2[j]);
    #pragma unroll
    for (int j = 0; j < 10; ++j) lg[j] = bo2[j];
    #pragma unroll 2
    for (int d = 0; d < HH; ++d) {
        #pragma unroll
        for (int j = 0; j < 10; ++j) lg[j] = fmaf(o2[d], Wo2[d*10 + j], lg[j]);
    }
    float m = lg[0];
    #pragma unroll
    for (int j = 1; j < 10; ++j) m = fmaxf(m, lg[j]);
    float ssum = 0.0f;
    #pragma unroll
    for (int j = 0; j < 10; ++j) ssum += expf(lg[j] - m);
    const float lse = m + logf(ssum);
    if (p < 10) {
        float v = 0.0f;
        #pragma unroll
        for (int j = 0; j < 10; ++j) v = (p == j) ? lg[j] : v;
        out[(size_t)b * 10 + p] = v - lse;
    }
}

extern "C" void kernel_launch(void* const* d_in, const int* in_sizes, int n_in,
                              void* d_out, int out_size, void* d_ws, size_t ws_size,
                              hipStream_t stream) {
    const float* x    = (const float*)d_in[0];
    const float* Wi0  = (const float*)d_in[1];
    const float* bi0  = (const float*)d_in[2];
    const float* Wi1  = (const float*)d_in[3];
    const float* bi1  = (const float*)d_in[4];
    const float* Wi2  = (const float*)d_in[5];
    const float* bi2  = (const float*)d_in[6];
    const float* We0a = (const float*)d_in[7];
    const float* be0a = (const float*)d_in[8];
    const float* We0b = (const float*)d_in[9];
    const float* be0b = (const float*)d_in[10];
    const float* We1a = (const float*)d_in[11];
    const float* be1a = (const float*)d_in[12];
    const float* We1b = (const float*)d_in[13];
    const float* be1b = (const float*)d_in[14];
    const float* Wo0  = (const float*)d_in[15];
    const float* bo0  = (const float*)d_in[16];
    const float* Wo1  = (const float*)d_in[17];
    const float* bo1  = (const float*)d_in[18];
    const float* Wo2  = (const float*)d_in[19];
    const float* bo2  = (const float*)d_in[20];
    float* out = (float*)d_out;
    double* ws = (double*)d_ws;

    prep_weights<<<dim3(1), dim3(256), 0, stream>>>(
        Wi0, bi0, Wi1, bi1, Wi2, bi2,
        We0a, be0a, We0b, be0b, We1a, be1a, We1b, be1b, ws);

    dgcnn_fused<<<dim3(8192), dim3(64), 0, stream>>>(
        x, ws, Wo0, bo0, Wo1, bo1, Wo2, bo2, out);
}